// Round 1
// baseline (980.664 us; speedup 1.0000x reference)
//
#include <hip/hip_runtime.h>
#include <math.h>

#define C 8192
#define D 1024
#define BATCH 1024
#define PM 0.95f
#define PMC 0.05f
#define INVT 10.0f

// ---------------------------------------------------------------------------
// zero rowsum[] (ws is poisoned 0xAA) and the scalar output
__global__ __launch_bounds__(256) void zero_kernel(float* __restrict__ rowsum,
                                                   float* __restrict__ out) {
    int i = blockIdx.x * 256 + threadIdx.x;
    if (i < C) rowsum[i] = 0.0f;
    if (i == 0) out[0] = 0.0f;
}

// ---------------------------------------------------------------------------
// EMA prototype update. One block per class. The scan is only sequential per
// label (each step touches exactly row labels[i]), so per-class chains run in
// parallel; within a class the chain is applied in sample order.
__global__ __launch_bounds__(256) void ema_kernel(const float* __restrict__ feat,
                                                  const int* __restrict__ labels,
                                                  float* __restrict__ protos) {
    __shared__ int sl[BATCH];
    __shared__ int matches[BATCH];
    __shared__ int nmatch_s;
    __shared__ float red[4];
    const int t = threadIdx.x;
    const int c = blockIdx.x;
    if (t == 0) nmatch_s = 0;
    for (int i = t; i < BATCH; i += 256) sl[i] = labels[i];
    __syncthreads();
    for (int i = t; i < BATCH; i += 256) {
        if (sl[i] == c) { int p = atomicAdd(&nmatch_s, 1); matches[p] = i; }
    }
    __syncthreads();
    const int n = nmatch_s;
    if (n == 0) return;                     // most blocks exit here
    if (t == 0) {                           // tiny insertion sort -> sample order
        for (int a = 1; a < n; ++a) {
            int key = matches[a]; int b = a - 1;
            while (b >= 0 && matches[b] > key) { matches[b + 1] = matches[b]; --b; }
            matches[b + 1] = key;
        }
    }
    __syncthreads();

    const int w = t >> 6, lane = t & 63;
    float4 v = *(const float4*)(protos + (size_t)c * D + t * 4);
    for (int m = 0; m < n; ++m) {
        const int idx = matches[m];
        const float4 f = *(const float4*)(feat + (size_t)idx * D + t * 4);
        v.x = v.x * PM + f.x * PMC;
        v.y = v.y * PM + f.y * PMC;
        v.z = v.z * PM + f.z * PMC;
        v.w = v.w * PM + f.w * PMC;
        float ss = v.x * v.x + v.y * v.y + v.z * v.z + v.w * v.w;
        #pragma unroll
        for (int off = 32; off > 0; off >>= 1) ss += __shfl_down(ss, off);
        if (lane == 0) red[w] = ss;
        __syncthreads();
        const float tot = red[0] + red[1] + red[2] + red[3];
        const float inv = 1.0f / fmaxf(sqrtf(tot), 1e-12f);
        v.x *= inv; v.y *= inv; v.z *= inv; v.w *= inv;
        __syncthreads();                    // red[] reuse next iteration
    }
    *(float4*)(protos + (size_t)c * D + t * 4) = v;
}

// ---------------------------------------------------------------------------
// Upper-triangle tiled Gram: 128x128 tile per block, 8x8 microtile per thread,
// BK=16. exp() in epilogue; row partials scattered to rowsum[i] and (off-diag
// tiles) rowsum[j] — symmetry halves the FLOPs.
__global__ __launch_bounds__(256) void gram_kernel(const float* __restrict__ P,
                                                   float* __restrict__ rowsum) {
    __shared__ alignas(16) float As[16][128];
    __shared__ alignas(16) float Bs[16][128];
    __shared__ float rpart[128];
    __shared__ float cpart[128];
    const int t = threadIdx.x;

    // linear block id -> upper-triangle tile (bi, bj), bj >= bi, 64x64 tiles
    int rem = blockIdx.x;
    int bi = 0;
    while (rem >= 64 - bi) { rem -= 64 - bi; ++bi; }
    const int bj = bi + rem;
    const int i0 = bi * 128, j0 = bj * 128;

    const int ty = t >> 4, tx = t & 15;      // compute mapping: 16x16 threads
    const int lrow = t >> 2, lq = t & 3;     // load mapping: 64 rows x 4 quads
    const float* Aptr = P + (size_t)(i0 + lrow) * D + lq * 4;
    const float* Bptr = P + (size_t)(j0 + lrow) * D + lq * 4;

    float acc[8][8];
    #pragma unroll
    for (int u = 0; u < 8; ++u)
        #pragma unroll
        for (int v = 0; v < 8; ++v) acc[u][v] = 0.0f;

    for (int kk = 0; kk < D; kk += 16) {
        const float4 a0 = *(const float4*)(Aptr + kk);
        const float4 a1 = *(const float4*)(Aptr + kk + (size_t)64 * D);
        const float4 b0 = *(const float4*)(Bptr + kk);
        const float4 b1 = *(const float4*)(Bptr + kk + (size_t)64 * D);
        __syncthreads();
        As[lq * 4 + 0][lrow] = a0.x; As[lq * 4 + 1][lrow] = a0.y;
        As[lq * 4 + 2][lrow] = a0.z; As[lq * 4 + 3][lrow] = a0.w;
        As[lq * 4 + 0][lrow + 64] = a1.x; As[lq * 4 + 1][lrow + 64] = a1.y;
        As[lq * 4 + 2][lrow + 64] = a1.z; As[lq * 4 + 3][lrow + 64] = a1.w;
        Bs[lq * 4 + 0][lrow] = b0.x; Bs[lq * 4 + 1][lrow] = b0.y;
        Bs[lq * 4 + 2][lrow] = b0.z; Bs[lq * 4 + 3][lrow] = b0.w;
        Bs[lq * 4 + 0][lrow + 64] = b1.x; Bs[lq * 4 + 1][lrow + 64] = b1.y;
        Bs[lq * 4 + 2][lrow + 64] = b1.z; Bs[lq * 4 + 3][lrow + 64] = b1.w;
        __syncthreads();
        #pragma unroll
        for (int k = 0; k < 16; ++k) {
            const float4 aa0 = *(const float4*)&As[k][ty * 8];
            const float4 aa1 = *(const float4*)&As[k][ty * 8 + 4];
            const float4 bb0 = *(const float4*)&Bs[k][tx * 8];
            const float4 bb1 = *(const float4*)&Bs[k][tx * 8 + 4];
            const float av[8] = {aa0.x, aa0.y, aa0.z, aa0.w, aa1.x, aa1.y, aa1.z, aa1.w};
            const float bv[8] = {bb0.x, bb0.y, bb0.z, bb0.w, bb1.x, bb1.y, bb1.z, bb1.w};
            #pragma unroll
            for (int u = 0; u < 8; ++u)
                #pragma unroll
                for (int v = 0; v < 8; ++v)
                    acc[u][v] = fmaf(av[u], bv[v], acc[u][v]);
        }
    }

    // epilogue: exp, tile-local row/col partial sums, one global atomic per row
    #pragma unroll
    for (int u = 0; u < 8; ++u)
        #pragma unroll
        for (int v = 0; v < 8; ++v)
            acc[u][v] = __expf(acc[u][v] * INVT);

    if (t < 128) { rpart[t] = 0.0f; cpart[t] = 0.0f; }
    __syncthreads();
    #pragma unroll
    for (int u = 0; u < 8; ++u) {
        float s = 0.0f;
        #pragma unroll
        for (int v = 0; v < 8; ++v) s += acc[u][v];
        atomicAdd(&rpart[ty * 8 + u], s);
    }
    if (bi != bj) {
        #pragma unroll
        for (int v = 0; v < 8; ++v) {
            float s = 0.0f;
            #pragma unroll
            for (int u = 0; u < 8; ++u) s += acc[u][v];
            atomicAdd(&cpart[tx * 8 + v], s);
        }
    }
    __syncthreads();
    if (t < 128) {
        atomicAdd(&rowsum[i0 + t], rpart[t]);
        if (bi != bj) atomicAdd(&rowsum[j0 + t], cpart[t]);
    }
}

// ---------------------------------------------------------------------------
// Per-row: subtract diagonal exp(selfdot*10), log, mean. One wave per row.
__global__ __launch_bounds__(256) void final_kernel(const float* __restrict__ P,
                                                    const float* __restrict__ rowsum,
                                                    float* __restrict__ out) {
    __shared__ float ws[4];
    const int t = threadIdx.x;
    const int w = t >> 6, lane = t & 63;
    const int row = blockIdx.x * 4 + w;
    const float4* pr = (const float4*)(P + (size_t)row * D);
    float s = 0.0f;
    #pragma unroll
    for (int i = lane; i < D / 4; i += 64) {
        const float4 v = pr[i];
        s += v.x * v.x + v.y * v.y + v.z * v.z + v.w * v.w;
    }
    #pragma unroll
    for (int off = 32; off > 0; off >>= 1) s += __shfl_down(s, off);
    if (lane == 0) {
        const float sum_neg = rowsum[row] - __expf(s * INVT);
        ws[w] = logf(sum_neg * (1.0f / (float)(C - 1)));
    }
    __syncthreads();
    if (t == 0)
        atomicAdd(out, (ws[0] + ws[1] + ws[2] + ws[3]) * (1.0f / (float)C));
}

// ---------------------------------------------------------------------------
extern "C" void kernel_launch(void* const* d_in, const int* in_sizes, int n_in,
                              void* d_out, int out_size, void* d_ws, size_t ws_size,
                              hipStream_t stream) {
    const float* feat = (const float*)d_in[0];
    const int* labels = (const int*)d_in[1];
    float* protos = (float*)d_in[2];   // updated in place; harness restores pristine inputs before every launch
    float* out = (float*)d_out;
    float* rowsum = (float*)d_ws;      // 8192 floats

    zero_kernel<<<32, 256, 0, stream>>>(rowsum, out);
    ema_kernel<<<C, 256, 0, stream>>>(feat, labels, protos);
    gram_kernel<<<(64 * 65) / 2, 256, 0, stream>>>(protos, rowsum);
    final_kernel<<<C / 4, 256, 0, stream>>>(protos, rowsum, out);
}

// Round 2
// 325.290 us; speedup vs baseline: 3.0147x; 3.0147x over previous
//
#include <hip/hip_runtime.h>
#include <math.h>

#define C 8192
#define D 1024
#define BATCH 1024
#define PM 0.95f
#define PMC 0.05f
#define INVT 10.0f

typedef __attribute__((ext_vector_type(8))) __bf16 bf16x8;
typedef __attribute__((ext_vector_type(4))) float f32x4;

#define GLOBAL_AS(p) ((const __attribute__((address_space(1))) void*)(p))
#define LDS_AS(p) ((__attribute__((address_space(3))) void*)(p))

// ---------------------------------------------------------------------------
__global__ __launch_bounds__(256) void zero_kernel(float* __restrict__ rowsum,
                                                   float* __restrict__ out) {
    int i = blockIdx.x * 256 + threadIdx.x;
    if (i < C) rowsum[i] = 0.0f;
    if (i == 0) out[0] = 0.0f;
}

// ---------------------------------------------------------------------------
// EMA prototype update. One block per class; per-class chains are independent,
// within a class the chain runs in sample order. (verified round 1)
__global__ __launch_bounds__(256) void ema_kernel(const float* __restrict__ feat,
                                                  const int* __restrict__ labels,
                                                  float* __restrict__ protos) {
    __shared__ int sl[BATCH];
    __shared__ int matches[BATCH];
    __shared__ int nmatch_s;
    __shared__ float red[4];
    const int t = threadIdx.x;
    const int c = blockIdx.x;
    if (t == 0) nmatch_s = 0;
    for (int i = t; i < BATCH; i += 256) sl[i] = labels[i];
    __syncthreads();
    for (int i = t; i < BATCH; i += 256) {
        if (sl[i] == c) { int p = atomicAdd(&nmatch_s, 1); matches[p] = i; }
    }
    __syncthreads();
    const int n = nmatch_s;
    if (n == 0) return;
    if (t == 0) {
        for (int a = 1; a < n; ++a) {
            int key = matches[a]; int b = a - 1;
            while (b >= 0 && matches[b] > key) { matches[b + 1] = matches[b]; --b; }
            matches[b + 1] = key;
        }
    }
    __syncthreads();

    const int w = t >> 6, lane = t & 63;
    float4 v = *(const float4*)(protos + (size_t)c * D + t * 4);
    for (int m = 0; m < n; ++m) {
        const int idx = matches[m];
        const float4 f = *(const float4*)(feat + (size_t)idx * D + t * 4);
        v.x = v.x * PM + f.x * PMC;
        v.y = v.y * PM + f.y * PMC;
        v.z = v.z * PM + f.z * PMC;
        v.w = v.w * PM + f.w * PMC;
        float ss = v.x * v.x + v.y * v.y + v.z * v.z + v.w * v.w;
        #pragma unroll
        for (int off = 32; off > 0; off >>= 1) ss += __shfl_down(ss, off);
        if (lane == 0) red[w] = ss;
        __syncthreads();
        const float tot = red[0] + red[1] + red[2] + red[3];
        const float inv = 1.0f / fmaxf(sqrtf(tot), 1e-12f);
        v.x *= inv; v.y *= inv; v.z *= inv; v.w *= inv;
        __syncthreads();
    }
    *(float4*)(protos + (size_t)c * D + t * 4) = v;
}

// ---------------------------------------------------------------------------
// Split fp32 protos -> bf16 hi/lo in MFMA-fragment tile order:
// tile (rt, kc) covers rows rt*16..+16, k kc*32..+32; element (r, h*8+j)
// stored at tile_base + (h*16+r)*8 + j  (== lane L*8+j with L=h*16+r), so a
// global_load_lds(dwordx4) of the tile lands exactly in fragment order.
__global__ __launch_bounds__(256) void prep_kernel(const float* __restrict__ P,
                                                   ushort* __restrict__ Phi,
                                                   ushort* __restrict__ Plo) {
    const int gid = blockIdx.x * 256 + threadIdx.x;   // one per 8 elements
    const int c = gid >> 7;
    const int k8 = gid & 127;
    const float* src = P + (size_t)c * D + k8 * 8;
    const float4 f0 = *(const float4*)src;
    const float4 f1 = *(const float4*)(src + 4);
    const int rt = c >> 4, r = c & 15, kc = k8 >> 2, h = k8 & 3;
    const size_t out = ((size_t)(rt * 32 + kc) * 64 + (h * 16 + r)) * 8;
    const float f[8] = {f0.x, f0.y, f0.z, f0.w, f1.x, f1.y, f1.z, f1.w};
    alignas(16) __bf16 hi8[8];
    alignas(16) __bf16 lo8[8];
    #pragma unroll
    for (int i = 0; i < 8; ++i) {
        const __bf16 hb = (__bf16)f[i];
        hi8[i] = hb;
        lo8[i] = (__bf16)(f[i] - (float)hb);
    }
    *(uint4*)(Phi + out) = *(const uint4*)hi8;
    *(uint4*)(Plo + out) = *(const uint4*)lo8;
}

// ---------------------------------------------------------------------------
// Split-bf16 MFMA Gram, upper triangle. 128x128 block tile, 4 waves each
// owning a 64x64 quadrant (4x4 grid of 16x16x32 MFMA tiles). Per BK=32 chunk:
// each wave stages 8 fragment-tiles via global_load_lds (w0:Ahi w1:Alo
// w2:Bhi w3:Blo), then 16 ds_read_b128 frag loads + 48 MFMA
// (hi*hi + hi*lo + lo*hi, fp32 acc; lo*lo dropped, <=2^-18 per dot).
// Diagonal elements are excluded here (exp zeroed), so rowsum == sum_neg.
__global__ __launch_bounds__(256) void gram_mfma_kernel(const ushort* __restrict__ Phi,
                                                        const ushort* __restrict__ Plo,
                                                        float* __restrict__ rowsum) {
    __shared__ alignas(16) ushort lds[4][8][512];   // [Ahi,Alo,Bhi,Blo][tile][16B*32lanes]
    __shared__ float rpart[128];
    __shared__ float cpart[128];
    const int t = threadIdx.x;
    const int w = t >> 6, lane = t & 63;

    int rem = blockIdx.x;
    int bi = 0;
    while (rem >= 64 - bi) { rem -= 64 - bi; ++bi; }
    const int bj = bi + rem;
    const bool diagBlock = (bi == bj);

    if (t < 128) { rpart[t] = 0.0f; cpart[t] = 0.0f; }

    // staging assignment
    const ushort* srcBase = (w == 1 || w == 3) ? Plo : Phi;
    const int rowTile0 = ((w < 2) ? bi : bj) * 8;
    ushort* myLds = &lds[w][0][0];

    f32x4 acc[4][4];
    #pragma unroll
    for (int a = 0; a < 4; ++a)
        #pragma unroll
        for (int b = 0; b < 4; ++b)
            acc[a][b] = (f32x4){0.f, 0.f, 0.f, 0.f};

    const int qi = w >> 1, qj = w & 1;

    for (int kc = 0; kc < D / 32; ++kc) {
        #pragma unroll
        for (int tt = 0; tt < 8; ++tt) {
            const ushort* g = srcBase + ((size_t)(rowTile0 + tt) * 32 + kc) * 512 + lane * 8;
            __builtin_amdgcn_global_load_lds(GLOBAL_AS(g), LDS_AS(myLds + tt * 512), 16, 0, 0);
        }
        __syncthreads();   // drains vmcnt -> tiles resident in LDS

        bf16x8 ah[4], al[4], bh[4], bl[4];
        #pragma unroll
        for (int ti = 0; ti < 4; ++ti) {
            const int at = qi * 4 + ti;
            ah[ti] = *(const bf16x8*)&lds[0][at][lane * 8];
            al[ti] = *(const bf16x8*)&lds[1][at][lane * 8];
        }
        #pragma unroll
        for (int tj = 0; tj < 4; ++tj) {
            const int bt = qj * 4 + tj;
            bh[tj] = *(const bf16x8*)&lds[2][bt][lane * 8];
            bl[tj] = *(const bf16x8*)&lds[3][bt][lane * 8];
        }
        #pragma unroll
        for (int ti = 0; ti < 4; ++ti)
            #pragma unroll
            for (int tj = 0; tj < 4; ++tj) {
                acc[ti][tj] = __builtin_amdgcn_mfma_f32_16x16x32_bf16(ah[ti], bh[tj], acc[ti][tj], 0, 0, 0);
                acc[ti][tj] = __builtin_amdgcn_mfma_f32_16x16x32_bf16(ah[ti], bl[tj], acc[ti][tj], 0, 0, 0);
                acc[ti][tj] = __builtin_amdgcn_mfma_f32_16x16x32_bf16(al[ti], bh[tj], acc[ti][tj], 0, 0, 0);
            }
        __syncthreads();   // all frag reads done before next chunk overwrites
    }

    // epilogue: exp, exclude diagonal, tile row/col sums, scatter to rowsum
    const int colInLane = lane & 15;
    const int rowQuad = lane >> 4;
    float csum[4] = {0.f, 0.f, 0.f, 0.f};
    #pragma unroll
    for (int ti = 0; ti < 4; ++ti) {
        float s[4] = {0.f, 0.f, 0.f, 0.f};
        #pragma unroll
        for (int tj = 0; tj < 4; ++tj) {
            #pragma unroll
            for (int reg = 0; reg < 4; ++reg) {
                const int ri = qi * 64 + ti * 16 + rowQuad * 4 + reg;
                const int cj = qj * 64 + tj * 16 + colInLane;
                float e = __expf(acc[ti][tj][reg] * INVT);
                if (diagBlock && ri == cj) e = 0.0f;
                s[reg] += e;
                csum[tj] += e;
            }
        }
        #pragma unroll
        for (int reg = 0; reg < 4; ++reg) {
            float v = s[reg];
            v += __shfl_xor(v, 1); v += __shfl_xor(v, 2);
            v += __shfl_xor(v, 4); v += __shfl_xor(v, 8);
            if (colInLane == 0)
                atomicAdd(&rpart[qi * 64 + ti * 16 + rowQuad * 4 + reg], v);
        }
    }
    if (!diagBlock) {
        #pragma unroll
        for (int tj = 0; tj < 4; ++tj) {
            float v = csum[tj];
            v += __shfl_xor(v, 16); v += __shfl_xor(v, 32);
            if (rowQuad == 0)
                atomicAdd(&cpart[qj * 64 + tj * 16 + colInLane], v);
        }
    }
    __syncthreads();
    if (t < 128) {
        atomicAdd(&rowsum[bi * 128 + t], rpart[t]);
        if (!diagBlock) atomicAdd(&rowsum[bj * 128 + t], cpart[t]);
    }
}

// ---------------------------------------------------------------------------
// MFMA path: rowsum already == sum_neg (diag excluded in gram epilogue)
__global__ __launch_bounds__(256) void final2_kernel(const float* __restrict__ rowsum,
                                                     float* __restrict__ out) {
    __shared__ float red[4];
    const int t = threadIdx.x;
    const int i = blockIdx.x * 256 + t;
    float v = logf(rowsum[i] * (1.0f / (float)(C - 1)));
    #pragma unroll
    for (int off = 32; off > 0; off >>= 1) v += __shfl_down(v, off);
    if ((t & 63) == 0) red[t >> 6] = v;
    __syncthreads();
    if (t == 0)
        atomicAdd(out, (red[0] + red[1] + red[2] + red[3]) * (1.0f / (float)C));
}

// ===========================================================================
// Fallback fp32 path (round-1 verified) — used only if ws_size is too small
// for the bf16 hi/lo buffers.
// ===========================================================================
__global__ __launch_bounds__(256) void gram_kernel(const float* __restrict__ P,
                                                   float* __restrict__ rowsum) {
    __shared__ alignas(16) float As[16][128];
    __shared__ alignas(16) float Bs[16][128];
    __shared__ float rpart[128];
    __shared__ float cpart[128];
    const int t = threadIdx.x;
    int rem = blockIdx.x;
    int bi = 0;
    while (rem >= 64 - bi) { rem -= 64 - bi; ++bi; }
    const int bj = bi + rem;
    const int i0 = bi * 128, j0 = bj * 128;
    const int ty = t >> 4, tx = t & 15;
    const int lrow = t >> 2, lq = t & 3;
    const float* Aptr = P + (size_t)(i0 + lrow) * D + lq * 4;
    const float* Bptr = P + (size_t)(j0 + lrow) * D + lq * 4;
    float acc[8][8];
    #pragma unroll
    for (int u = 0; u < 8; ++u)
        #pragma unroll
        for (int v = 0; v < 8; ++v) acc[u][v] = 0.0f;
    for (int kk = 0; kk < D; kk += 16) {
        const float4 a0 = *(const float4*)(Aptr + kk);
        const float4 a1 = *(const float4*)(Aptr + kk + (size_t)64 * D);
        const float4 b0 = *(const float4*)(Bptr + kk);
        const float4 b1 = *(const float4*)(Bptr + kk + (size_t)64 * D);
        __syncthreads();
        As[lq * 4 + 0][lrow] = a0.x; As[lq * 4 + 1][lrow] = a0.y;
        As[lq * 4 + 2][lrow] = a0.z; As[lq * 4 + 3][lrow] = a0.w;
        As[lq * 4 + 0][lrow + 64] = a1.x; As[lq * 4 + 1][lrow + 64] = a1.y;
        As[lq * 4 + 2][lrow + 64] = a1.z; As[lq * 4 + 3][lrow + 64] = a1.w;
        Bs[lq * 4 + 0][lrow] = b0.x; Bs[lq * 4 + 1][lrow] = b0.y;
        Bs[lq * 4 + 2][lrow] = b0.z; Bs[lq * 4 + 3][lrow] = b0.w;
        Bs[lq * 4 + 0][lrow + 64] = b1.x; Bs[lq * 4 + 1][lrow + 64] = b1.y;
        Bs[lq * 4 + 2][lrow + 64] = b1.z; Bs[lq * 4 + 3][lrow + 64] = b1.w;
        __syncthreads();
        #pragma unroll
        for (int k = 0; k < 16; ++k) {
            const float4 aa0 = *(const float4*)&As[k][ty * 8];
            const float4 aa1 = *(const float4*)&As[k][ty * 8 + 4];
            const float4 bb0 = *(const float4*)&Bs[k][tx * 8];
            const float4 bb1 = *(const float4*)&Bs[k][tx * 8 + 4];
            const float av[8] = {aa0.x, aa0.y, aa0.z, aa0.w, aa1.x, aa1.y, aa1.z, aa1.w};
            const float bv[8] = {bb0.x, bb0.y, bb0.z, bb0.w, bb1.x, bb1.y, bb1.z, bb1.w};
            #pragma unroll
            for (int u = 0; u < 8; ++u)
                #pragma unroll
                for (int v = 0; v < 8; ++v)
                    acc[u][v] = fmaf(av[u], bv[v], acc[u][v]);
        }
    }
    #pragma unroll
    for (int u = 0; u < 8; ++u)
        #pragma unroll
        for (int v = 0; v < 8; ++v)
            acc[u][v] = __expf(acc[u][v] * INVT);
    if (t < 128) { rpart[t] = 0.0f; cpart[t] = 0.0f; }
    __syncthreads();
    #pragma unroll
    for (int u = 0; u < 8; ++u) {
        float s = 0.0f;
        #pragma unroll
        for (int v = 0; v < 8; ++v) s += acc[u][v];
        atomicAdd(&rpart[ty * 8 + u], s);
    }
    if (bi != bj) {
        #pragma unroll
        for (int v = 0; v < 8; ++v) {
            float s = 0.0f;
            #pragma unroll
            for (int u = 0; u < 8; ++u) s += acc[u][v];
            atomicAdd(&cpart[tx * 8 + v], s);
        }
    }
    __syncthreads();
    if (t < 128) {
        atomicAdd(&rowsum[i0 + t], rpart[t]);
        if (bi != bj) atomicAdd(&rowsum[j0 + t], cpart[t]);
    }
}

__global__ __launch_bounds__(256) void final_kernel(const float* __restrict__ P,
                                                    const float* __restrict__ rowsum,
                                                    float* __restrict__ out) {
    __shared__ float ws[4];
    const int t = threadIdx.x;
    const int w = t >> 6, lane = t & 63;
    const int row = blockIdx.x * 4 + w;
    const float4* pr = (const float4*)(P + (size_t)row * D);
    float s = 0.0f;
    #pragma unroll
    for (int i = lane; i < D / 4; i += 64) {
        const float4 v = pr[i];
        s += v.x * v.x + v.y * v.y + v.z * v.z + v.w * v.w;
    }
    #pragma unroll
    for (int off = 32; off > 0; off >>= 1) s += __shfl_down(s, off);
    if (lane == 0) {
        const float sum_neg = rowsum[row] - __expf(s * INVT);
        ws[w] = logf(sum_neg * (1.0f / (float)(C - 1)));
    }
    __syncthreads();
    if (t == 0)
        atomicAdd(out, (ws[0] + ws[1] + ws[2] + ws[3]) * (1.0f / (float)C));
}

// ---------------------------------------------------------------------------
extern "C" void kernel_launch(void* const* d_in, const int* in_sizes, int n_in,
                              void* d_out, int out_size, void* d_ws, size_t ws_size,
                              hipStream_t stream) {
    const float* feat = (const float*)d_in[0];
    const int* labels = (const int*)d_in[1];
    float* protos = (float*)d_in[2];   // harness restores pristine inputs each call
    float* out = (float*)d_out;
    float* rowsum = (float*)d_ws;

    const size_t bf16_bytes = (size_t)C * D * sizeof(ushort);       // 16 MiB each
    const size_t need = 32768 + 2 * bf16_bytes;

    zero_kernel<<<32, 256, 0, stream>>>(rowsum, out);
    ema_kernel<<<C, 256, 0, stream>>>(feat, labels, protos);

    if (ws_size >= need) {
        ushort* Phi = (ushort*)((char*)d_ws + 32768);
        ushort* Plo = (ushort*)((char*)d_ws + 32768 + bf16_bytes);
        prep_kernel<<<(C * 128) / 256, 256, 0, stream>>>(protos, Phi, Plo);
        gram_mfma_kernel<<<(64 * 65) / 2, 256, 0, stream>>>(Phi, Plo, rowsum);
        final2_kernel<<<C / 256, 256, 0, stream>>>(rowsum, out);
    } else {
        gram_kernel<<<(64 * 65) / 2, 256, 0, stream>>>(protos, rowsum);
        final_kernel<<<C / 4, 256, 0, stream>>>(protos, rowsum, out);
    }
}